// Round 2
// baseline (5944.989 us; speedup 1.0000x reference)
//
#include <hip/hip_runtime.h>
#include <math.h>

#define VOCAB 10000
#define DIM 64
#define LTOK 8
#define DGPT 256
#define NHEAD 4
#define NNODES 8192
#define NEDGES 2048
#define FDIM 512                 // LTOK*DIM
#define NROWS (NEDGES*LTOK)      // 16384

// ---------------- mask / labels ----------------
__global__ __launch_bounds__(256) void k_mask(const int* __restrict__ etok,
                                              const int* __restrict__ mrows,
                                              float* __restrict__ labels,
                                              int* __restrict__ mtok) {
    int i = blockIdx.x * 256 + threadIdx.x;     // < 16384
    int e = i >> 3;
    int t = etok[i];
    bool m = (mrows[e] != 0) && (t > 3);        // SPECIAL = {0,1,2,3}
    labels[i] = m ? (float)t : -100.0f;
    mtok[i] = m ? 4 : t;                        // MASK_ID = 4
}

// ---------------- embedding gather ----------------
__global__ __launch_bounds__(256) void k_embed(const int* __restrict__ tok,
                                               const float* __restrict__ emb,
                                               float* __restrict__ outf, int total) {
    int i = blockIdx.x * 256 + threadIdx.x;
    if (i >= total) return;
    int d = i & 63;
    int tl = i >> 6;
    outf[i] = emb[(size_t)tok[tl] * DIM + d];
}

// ---------------- eh = h[src] + h[dst] ----------------
__global__ __launch_bounds__(256) void k_eh(const float* __restrict__ h,
                                            const int* __restrict__ src,
                                            const int* __restrict__ dst,
                                            float* __restrict__ eh) {
    int i = blockIdx.x * 256 + threadIdx.x;     // < 2048*512
    int e = i >> 9; int f = i & 511;
    eh[i] = h[(size_t)src[e] * FDIM + f] + h[(size_t)dst[e] * FDIM + f];
}

// ---------------- generic tiled fp32 GEMM with fused epilogue (64x64 tile) ----------------
// out[M,N] = act(A[M,K] @ W[K,N] + bias[N] + res[resRow,N]) ; optional atomic scatter by dstIdx
// act: 0 none, 1 relu, 2 gelu(tanh approx)
__global__ __launch_bounds__(256) void gemm_kernel(
    const float* __restrict__ A, const float* __restrict__ W,
    const float* __restrict__ bias, const float* __restrict__ res,
    const int* __restrict__ resIdx, const int* __restrict__ dstIdx,
    float* __restrict__ out, int M, int N, int K, int act)
{
    __shared__ float As[16][68];   // [k][row] (+pad)
    __shared__ float Ws[16][68];   // [k][col] (+pad)
    int tid = threadIdx.x;
    int row0 = blockIdx.x * 64, col0 = blockIdx.y * 64;
    int ty = tid >> 4, tx = tid & 15;
    float acc[4][4] = {};
    int arow = tid >> 2;            // 0..63
    int acol4 = (tid & 3) * 4;      // 0,4,8,12
    int wrow = tid >> 4;            // 0..15
    int wcol4 = (tid & 15) * 4;

    for (int kc = 0; kc < K; kc += 16) {
        float4 av = *(const float4*)&A[(size_t)(row0 + arow) * K + kc + acol4];
        float4 wv = *(const float4*)&W[(size_t)(kc + wrow) * N + col0 + wcol4];
        __syncthreads();
        As[acol4 + 0][arow] = av.x;
        As[acol4 + 1][arow] = av.y;
        As[acol4 + 2][arow] = av.z;
        As[acol4 + 3][arow] = av.w;
        *(float4*)&Ws[wrow][wcol4] = wv;
        __syncthreads();
#pragma unroll
        for (int kk = 0; kk < 16; kk++) {
            float4 a4 = *(const float4*)&As[kk][ty * 4];
            float4 w4 = *(const float4*)&Ws[kk][tx * 4];
            float ar[4] = {a4.x, a4.y, a4.z, a4.w};
            float wr[4] = {w4.x, w4.y, w4.z, w4.w};
#pragma unroll
            for (int i = 0; i < 4; i++)
#pragma unroll
                for (int j = 0; j < 4; j++)
                    acc[i][j] += ar[i] * wr[j];
        }
    }

    const float c0 = 0.7978845608028654f, c1 = 0.044715f;
#pragma unroll
    for (int i = 0; i < 4; i++) {
        int row = row0 + ty * 4 + i;
        int rrow = resIdx ? resIdx[row] : row;
#pragma unroll
        for (int j = 0; j < 4; j++) {
            int col = col0 + tx * 4 + j;
            float v = acc[i][j];
            if (bias) v += bias[col];
            if (res)  v += res[(size_t)rrow * N + col];
            if (act == 1) v = fmaxf(v, 0.0f);
            else if (act == 2) { float t = v; v = 0.5f * t * (1.0f + tanhf(c0 * (t + c1 * t * t * t))); }
            if (dstIdx) atomicAdd(&out[(size_t)dstIdx[row] * N + col], v);
            else out[(size_t)row * N + col] = v;
        }
    }
}

// ---------------- 128x128 tile, 8x8 micro-tile fp32 GEMM (for big GEMMs) ----------------
// out[M,N] = act(A[M,K] @ W[K,N] + bias[N] + res[M,N]); M%128==0, N%128==0, K%16==0
__global__ __launch_bounds__(256, 3) void gemm128(
    const float* __restrict__ A, const float* __restrict__ W,
    const float* __restrict__ bias, const float* __restrict__ res,
    float* __restrict__ out, int M, int N, int K, int act)
{
    __shared__ float As[16][132];   // [k][row]
    __shared__ float Ws[16][132];   // [k][col]
    int tid = threadIdx.x;
    int row0 = blockIdx.x * 128, col0 = blockIdx.y * 128;
    int ty = tid >> 4, tx = tid & 15;       // 16x16 threads
    float acc[8][8] = {};

    for (int kc = 0; kc < K; kc += 16) {
        float4 av[2], wv[2];
#pragma unroll
        for (int q = 0; q < 2; q++) {
            int fidx = q * 256 + tid;           // 0..511
            int arow = fidx >> 2;               // 0..127
            int ak4  = (fidx & 3) * 4;          // 0,4,8,12
            av[q] = *(const float4*)&A[(size_t)(row0 + arow) * K + kc + ak4];
            int wrow = fidx >> 5;               // 0..15
            int wc4  = (fidx & 31) * 4;         // 0..124
            wv[q] = *(const float4*)&W[(size_t)(kc + wrow) * N + col0 + wc4];
        }
        __syncthreads();
#pragma unroll
        for (int q = 0; q < 2; q++) {
            int fidx = q * 256 + tid;
            int arow = fidx >> 2;
            int ak4  = (fidx & 3) * 4;
            As[ak4 + 0][arow] = av[q].x;
            As[ak4 + 1][arow] = av[q].y;
            As[ak4 + 2][arow] = av[q].z;
            As[ak4 + 3][arow] = av[q].w;
            int wrow = fidx >> 5;
            int wc4  = (fidx & 31) * 4;
            *(float4*)&Ws[wrow][wc4] = wv[q];
        }
        __syncthreads();
#pragma unroll
        for (int kk = 0; kk < 16; kk++) {
            float4 aA = *(const float4*)&As[kk][ty * 4];
            float4 aB = *(const float4*)&As[kk][64 + ty * 4];
            float4 wA = *(const float4*)&Ws[kk][tx * 4];
            float4 wB = *(const float4*)&Ws[kk][64 + tx * 4];
            float ar[8] = {aA.x, aA.y, aA.z, aA.w, aB.x, aB.y, aB.z, aB.w};
            float wr[8] = {wA.x, wA.y, wA.z, wA.w, wB.x, wB.y, wB.z, wB.w};
#pragma unroll
            for (int i = 0; i < 8; i++)
#pragma unroll
                for (int j = 0; j < 8; j++)
                    acc[i][j] += ar[i] * wr[j];
        }
    }

    const float c0 = 0.7978845608028654f, c1 = 0.044715f;
#pragma unroll
    for (int i = 0; i < 8; i++) {
        int row = row0 + (i < 4 ? ty * 4 + i : 64 + ty * 4 + (i - 4));
#pragma unroll
        for (int j = 0; j < 8; j++) {
            int col = col0 + (j < 4 ? tx * 4 + j : 64 + tx * 4 + (j - 4));
            float v = acc[i][j];
            if (bias) v += bias[col];
            if (res)  v += res[(size_t)row * N + col];
            if (act == 1) v = fmaxf(v, 0.0f);
            else if (act == 2) { float t = v; v = 0.5f * t * (1.0f + tanhf(c0 * (t + c1 * t * t * t))); }
            out[(size_t)row * N + col] = v;
        }
    }
}

// ---------------- per-edge attention (S=8, NH=4, hd=64) ----------------
__global__ __launch_bounds__(256) void k_attn(const float* __restrict__ q,
                                              const float* __restrict__ k,
                                              const float* __restrict__ v,
                                              float* __restrict__ o) {
    __shared__ float qs[8 * 256], ks[8 * 256], vs[8 * 256];
    __shared__ float sc[4 * 8 * 8];
    int b = blockIdx.x, t = threadIdx.x;
    const size_t base = (size_t)b * (8 * 256);
    for (int i = t; i < 2048; i += 256) { qs[i] = q[base + i]; ks[i] = k[base + i]; vs[i] = v[base + i]; }
    __syncthreads();
    {
        int h = t >> 6, sq = (t >> 3) & 7, sk = t & 7;
        float acc = 0.0f;
#pragma unroll
        for (int d = 0; d < 64; d++) acc += qs[sq * 256 + h * 64 + d] * ks[sk * 256 + h * 64 + d];
        sc[t] = acc * 0.125f;     // 1/sqrt(64)
    }
    __syncthreads();
    if (t < 32) {
        int h = t >> 3, sq = t & 7;
        float* r = &sc[h * 64 + sq * 8];
        float M = r[0];
        for (int i = 1; i < 8; i++) M = fmaxf(M, r[i]);
        float S = 0.0f, ex[8];
        for (int i = 0; i < 8; i++) { ex[i] = __expf(r[i] - M); S += ex[i]; }
        float inv = 1.0f / S;
        for (int i = 0; i < 8; i++) r[i] = ex[i] * inv;
    }
    __syncthreads();
    {
        int col = t; int h = col >> 6;
#pragma unroll
        for (int sq = 0; sq < 8; sq++) {
            float a = 0.0f;
#pragma unroll
            for (int sk = 0; sk < 8; sk++) a += sc[h * 64 + sq * 8 + sk] * vs[sk * 256 + col];
            o[base + sq * 256 + col] = a;
        }
    }
}

// ---------------- logits = y @ emb^T, written into probs buffer ----------------
// Each thread owns TWO vocab columns (emb rows register-resident: 128 VGPRs),
// 8 FMA per broadcast ds_read_b128. Stores lane-contiguous along vocab.
// grid = (NROWS/256, ceil(VOCAB/512)) = (64, 20) = 1280 blocks.
__global__ __launch_bounds__(256, 3) void k_logits(const float* __restrict__ Y,
                                                   const float* __restrict__ emb,
                                                   float* __restrict__ probs) {
    __shared__ float ys[128][64];   // 32 KB
    int t = threadIdx.x;
    int v0 = blockIdx.y * 512 + t;          // always < VOCAB (<= 9983)
    int v1 = v0 + 256;
    bool v1ok = v1 < VOCAB;

    float er0[64], er1[64];
    {
        const float4* ep0 = (const float4*)&emb[(size_t)v0 * DIM];
        const float4* ep1 = (const float4*)&emb[(size_t)(v1ok ? v1 : 0) * DIM];
#pragma unroll
        for (int i = 0; i < 16; i++) {
            float4 a = ep0[i], b = ep1[i];
            er0[4*i+0] = a.x; er0[4*i+1] = a.y; er0[4*i+2] = a.z; er0[4*i+3] = a.w;
            er1[4*i+0] = b.x; er1[4*i+1] = b.y; er1[4*i+2] = b.z; er1[4*i+3] = b.w;
        }
    }

    int r0 = blockIdx.x * 256;
    for (int c = 0; c < 256; c += 128) {
        __syncthreads();           // protect previous chunk's reads
#pragma unroll
        for (int q = 0; q < 8; q++) {
            int fidx = q * 256 + t;            // 0..2047
            int row = fidx >> 4;               // 0..127
            int k4 = (fidx & 15) * 4;          // 0..60
            *(float4*)&ys[row][k4] = *(const float4*)&Y[(size_t)(r0 + c + row) * DIM + k4];
        }
        __syncthreads();

        for (int r = 0; r < 128; r += 4) {
            float a00 = 0.f, a10 = 0.f, a20 = 0.f, a30 = 0.f;
            float a01 = 0.f, a11 = 0.f, a21 = 0.f, a31 = 0.f;
#pragma unroll
            for (int kk = 0; kk < 16; kk++) {
                float4 y0 = *(const float4*)&ys[r + 0][kk * 4];
                float4 y1 = *(const float4*)&ys[r + 1][kk * 4];
                float4 y2 = *(const float4*)&ys[r + 2][kk * 4];
                float4 y3 = *(const float4*)&ys[r + 3][kk * 4];
                float e0 = er0[4*kk+0], e1 = er0[4*kk+1], e2 = er0[4*kk+2], e3 = er0[4*kk+3];
                float f0 = er1[4*kk+0], f1 = er1[4*kk+1], f2 = er1[4*kk+2], f3 = er1[4*kk+3];
                a00 += y0.x * e0; a00 += y0.y * e1; a00 += y0.z * e2; a00 += y0.w * e3;
                a10 += y1.x * e0; a10 += y1.y * e1; a10 += y1.z * e2; a10 += y1.w * e3;
                a20 += y2.x * e0; a20 += y2.y * e1; a20 += y2.z * e2; a20 += y2.w * e3;
                a30 += y3.x * e0; a30 += y3.y * e1; a30 += y3.z * e2; a30 += y3.w * e3;
                a01 += y0.x * f0; a01 += y0.y * f1; a01 += y0.z * f2; a01 += y0.w * f3;
                a11 += y1.x * f0; a11 += y1.y * f1; a11 += y1.z * f2; a11 += y1.w * f3;
                a21 += y2.x * f0; a21 += y2.y * f1; a21 += y2.z * f2; a21 += y2.w * f3;
                a31 += y3.x * f0; a31 += y3.y * f1; a31 += y3.z * f2; a31 += y3.w * f3;
            }
            size_t base = (size_t)(r0 + c + r) * VOCAB;
            probs[base             + v0] = a00;
            probs[base +     VOCAB + v0] = a10;
            probs[base + 2 * VOCAB + v0] = a20;
            probs[base + 3 * VOCAB + v0] = a30;
            if (v1ok) {
                probs[base             + v1] = a01;
                probs[base +     VOCAB + v1] = a11;
                probs[base + 2 * VOCAB + v1] = a21;
                probs[base + 3 * VOCAB + v1] = a31;
            }
        }
    }
}

// ---------------- in-place row softmax over VOCAB (row cached in LDS) ----------------
__global__ __launch_bounds__(256) void k_softmax(float* __restrict__ probs) {
    __shared__ float4 sdata[VOCAB / 4];   // 2500 float4 = 40000 B
    __shared__ float wred[8];
    int t = threadIdx.x;
    float4* prow = (float4*)&probs[(size_t)blockIdx.x * VOCAB];

    // pass 1: load + local max
    float m = -1e30f;
#pragma unroll
    for (int i = 0; i < 10; i++) {
        int j = t + 256 * i;
        if (j < VOCAB / 4) {
            float4 v4 = prow[j];
            sdata[j] = v4;
            m = fmaxf(fmaxf(fmaxf(m, v4.x), v4.y), fmaxf(v4.z, v4.w));
        }
    }
#pragma unroll
    for (int off = 32; off; off >>= 1) m = fmaxf(m, __shfl_xor(m, off, 64));
    if ((t & 63) == 0) wred[t >> 6] = m;
    __syncthreads();
    float M = fmaxf(fmaxf(wred[0], wred[1]), fmaxf(wred[2], wred[3]));

    // pass 2: exp + local sum (store exp back to LDS)
    float s = 0.0f;
#pragma unroll
    for (int i = 0; i < 10; i++) {
        int j = t + 256 * i;
        if (j < VOCAB / 4) {
            float4 v4 = sdata[j];
            v4.x = __expf(v4.x - M); v4.y = __expf(v4.y - M);
            v4.z = __expf(v4.z - M); v4.w = __expf(v4.w - M);
            sdata[j] = v4;
            s += v4.x + v4.y + v4.z + v4.w;
        }
    }
#pragma unroll
    for (int off = 32; off; off >>= 1) s += __shfl_xor(s, off, 64);
    if ((t & 63) == 0) wred[4 + (t >> 6)] = s;
    __syncthreads();
    float Sinv = 1.0f / (wred[4] + wred[5] + wred[6] + wred[7]);

    // pass 3: scale + store
#pragma unroll
    for (int i = 0; i < 10; i++) {
        int j = t + 256 * i;
        if (j < VOCAB / 4) {
            float4 v4 = sdata[j];
            v4.x *= Sinv; v4.y *= Sinv; v4.z *= Sinv; v4.w *= Sinv;
            prow[j] = v4;
        }
    }
}

extern "C" void kernel_launch(void* const* d_in, const int* in_sizes, int n_in,
                              void* d_out, int out_size, void* d_ws, size_t ws_size,
                              hipStream_t stream) {
    const int* node_tokens = (const int*)d_in[0];
    const int* edge_tokens = (const int*)d_in[1];
    const int* edge_index  = (const int*)d_in[2];
    const int* mask_rows   = (const int*)d_in[3];   // bool passed as int32
    const float* emb    = (const float*)d_in[4];
    const float* W_msg  = (const float*)d_in[5];
    const float* W_node = (const float*)d_in[6];
    const float* lc1_w  = (const float*)d_in[7];
    const float* lc1_b  = (const float*)d_in[8];
    const float* lc2_w  = (const float*)d_in[9];
    const float* lc2_b  = (const float*)d_in[10];
    const float* Wq     = (const float*)d_in[11];
    const float* Wk     = (const float*)d_in[12];
    const float* Wv     = (const float*)d_in[13];
    const float* Wo     = (const float*)d_in[14];
    const float* Wf1    = (const float*)d_in[15];
    const float* Wf2    = (const float*)d_in[16];

    const int* src = edge_index;
    const int* dst = edge_index + NEDGES;

    float* labels = (float*)d_out;
    float* probs  = labels + NROWS;

    float* ws = (float*)d_ws;
    float* X   = ws;                  // [8192,512]
    float* E_  = X   + 4194304;       // [2048,512]
    float* AGG = E_  + 1048576;       // [8192,512], becomes H in-place
    float* EH  = AGG + 4194304;       // [2048,512] == z rows [16384,64]
    float* Z1  = EH  + 1048576;       // [16384,256]
    float* Q_  = Z1  + 4194304;
    float* K_  = Q_  + 4194304;
    float* Vv  = K_  + 4194304;
    float* O_  = Vv  + 4194304;
    float* X2  = O_  + 4194304;
    float* U_  = X2  + 4194304;       // [16384,1024]
    float* Y2  = U_  + 16777216;      // [16384,256]
    float* Y_  = Y2  + 4194304;       // [16384,64]
    int*  MTOK = (int*)(Y_ + 1048576);

    // zero agg for scatter-add
    hipMemsetAsync(AGG, 0, (size_t)NNODES * FDIM * sizeof(float), stream);

    // masking + labels
    k_mask<<<NROWS / 256, 256, 0, stream>>>(edge_tokens, mask_rows, labels, MTOK);

    // embeddings
    k_embed<<<(NNODES * FDIM) / 256, 256, 0, stream>>>(node_tokens, emb, X, NNODES * FDIM);
    k_embed<<<(NEDGES * FDIM) / 256, 256, 0, stream>>>(MTOK, emb, E_, NEDGES * FDIM);

    // msg = relu(e @ W_msg + x[src]); scatter-add to agg[dst]
    gemm_kernel<<<dim3(NEDGES / 64, FDIM / 64), 256, 0, stream>>>(
        E_, W_msg, nullptr, X, src, dst, AGG, NEDGES, FDIM, FDIM, 1);

    // h = relu(x @ W_node + agg)   (in-place into AGG) — big GEMM, 128-tile
    gemm128<<<dim3(NNODES / 128, FDIM / 128), 256, 0, stream>>>(
        X, W_node, nullptr, AGG, AGG, NNODES, FDIM, FDIM, 1);

    // eh = h[src] + h[dst]
    k_eh<<<(NEDGES * FDIM) / 256, 256, 0, stream>>>(AGG, src, dst, EH);

    // z1 = eh @ lc1_w + lc1_b    ([16384,64] @ [64,256])
    gemm_kernel<<<dim3(NROWS / 64, DGPT / 64), 256, 0, stream>>>(
        EH, lc1_w, lc1_b, nullptr, nullptr, nullptr, Z1, NROWS, DGPT, DIM, 0);

    // q,k,v projections
    gemm_kernel<<<dim3(NROWS / 64, DGPT / 64), 256, 0, stream>>>(
        Z1, Wq, nullptr, nullptr, nullptr, nullptr, Q_, NROWS, DGPT, DGPT, 0);
    gemm_kernel<<<dim3(NROWS / 64, DGPT / 64), 256, 0, stream>>>(
        Z1, Wk, nullptr, nullptr, nullptr, nullptr, K_, NROWS, DGPT, DGPT, 0);
    gemm_kernel<<<dim3(NROWS / 64, DGPT / 64), 256, 0, stream>>>(
        Z1, Wv, nullptr, nullptr, nullptr, nullptr, Vv, NROWS, DGPT, DGPT, 0);

    // attention
    k_attn<<<NEDGES, 256, 0, stream>>>(Q_, K_, Vv, O_);

    // x2 = z1 + o @ Wo
    gemm_kernel<<<dim3(NROWS / 64, DGPT / 64), 256, 0, stream>>>(
        O_, Wo, nullptr, Z1, nullptr, nullptr, X2, NROWS, DGPT, DGPT, 0);

    // u = gelu(x2 @ Wf1) — big GEMM, 128-tile
    gemm128<<<dim3(NROWS / 128, (4 * DGPT) / 128), 256, 0, stream>>>(
        X2, Wf1, nullptr, nullptr, U_, NROWS, 4 * DGPT, DGPT, 2);

    // y2 = x2 + u @ Wf2 — big GEMM, 128-tile
    gemm128<<<dim3(NROWS / 128, DGPT / 128), 256, 0, stream>>>(
        U_, Wf2, nullptr, X2, Y2, NROWS, DGPT, 4 * DGPT, 0);

    // y = y2 @ lc2_w + lc2_b
    gemm_kernel<<<dim3(NROWS / 64, DIM / 64), 256, 0, stream>>>(
        Y2, lc2_w, lc2_b, nullptr, nullptr, nullptr, Y_, NROWS, DIM, DGPT, 0);

    // logits into probs buffer (one pass), then in-place row softmax
    k_logits<<<dim3(NROWS / 256, (VOCAB + 511) / 512), 256, 0, stream>>>(Y_, emb, probs);
    k_softmax<<<NROWS, 256, 0, stream>>>(probs);
}

// Round 3
// 1872.851 us; speedup vs baseline: 3.1743x; 3.1743x over previous
//
#include <hip/hip_runtime.h>
#include <math.h>

#define VOCAB 10000
#define DIM 64
#define LTOK 8
#define DGPT 256
#define NHEAD 4
#define NNODES 8192
#define NEDGES 2048
#define FDIM 512                 // LTOK*DIM
#define NROWS (NEDGES*LTOK)      // 16384

// ---------------- mask / labels ----------------
__global__ __launch_bounds__(256) void k_mask(const int* __restrict__ etok,
                                              const int* __restrict__ mrows,
                                              float* __restrict__ labels,
                                              int* __restrict__ mtok) {
    int i = blockIdx.x * 256 + threadIdx.x;     // < 16384
    int e = i >> 3;
    int t = etok[i];
    bool m = (mrows[e] != 0) && (t > 3);        // SPECIAL = {0,1,2,3}
    labels[i] = m ? (float)t : -100.0f;
    mtok[i] = m ? 4 : t;                        // MASK_ID = 4
}

// ---------------- embedding gather ----------------
__global__ __launch_bounds__(256) void k_embed(const int* __restrict__ tok,
                                               const float* __restrict__ emb,
                                               float* __restrict__ outf, int total) {
    int i = blockIdx.x * 256 + threadIdx.x;
    if (i >= total) return;
    int d = i & 63;
    int tl = i >> 6;
    outf[i] = emb[(size_t)tok[tl] * DIM + d];
}

// ---------------- eh = h[src] + h[dst] ----------------
__global__ __launch_bounds__(256) void k_eh(const float* __restrict__ h,
                                            const int* __restrict__ src,
                                            const int* __restrict__ dst,
                                            float* __restrict__ eh) {
    int i = blockIdx.x * 256 + threadIdx.x;     // < 2048*512
    int e = i >> 9; int f = i & 511;
    eh[i] = h[(size_t)src[e] * FDIM + f] + h[(size_t)dst[e] * FDIM + f];
}

// ---------------- generic tiled fp32 GEMM with fused epilogue (64x64 tile) ----------------
// out[M,N] = act(A[M,K] @ W[K,N] + bias[N] + res[resRow,N]) ; optional atomic scatter by dstIdx
// act: 0 none, 1 relu, 2 gelu(tanh approx)
__global__ __launch_bounds__(256) void gemm_kernel(
    const float* __restrict__ A, const float* __restrict__ W,
    const float* __restrict__ bias, const float* __restrict__ res,
    const int* __restrict__ resIdx, const int* __restrict__ dstIdx,
    float* __restrict__ out, int M, int N, int K, int act)
{
    __shared__ float As[16][68];   // [k][row] (+pad)
    __shared__ float Ws[16][68];   // [k][col] (+pad)
    int tid = threadIdx.x;
    int row0 = blockIdx.x * 64, col0 = blockIdx.y * 64;
    int ty = tid >> 4, tx = tid & 15;
    float acc[4][4] = {};
    int arow = tid >> 2;            // 0..63
    int acol4 = (tid & 3) * 4;      // 0,4,8,12
    int wrow = tid >> 4;            // 0..15
    int wcol4 = (tid & 15) * 4;

    for (int kc = 0; kc < K; kc += 16) {
        float4 av = *(const float4*)&A[(size_t)(row0 + arow) * K + kc + acol4];
        float4 wv = *(const float4*)&W[(size_t)(kc + wrow) * N + col0 + wcol4];
        __syncthreads();
        As[acol4 + 0][arow] = av.x;
        As[acol4 + 1][arow] = av.y;
        As[acol4 + 2][arow] = av.z;
        As[acol4 + 3][arow] = av.w;
        *(float4*)&Ws[wrow][wcol4] = wv;
        __syncthreads();
#pragma unroll
        for (int kk = 0; kk < 16; kk++) {
            float4 a4 = *(const float4*)&As[kk][ty * 4];
            float4 w4 = *(const float4*)&Ws[kk][tx * 4];
            float ar[4] = {a4.x, a4.y, a4.z, a4.w};
            float wr[4] = {w4.x, w4.y, w4.z, w4.w};
#pragma unroll
            for (int i = 0; i < 4; i++)
#pragma unroll
                for (int j = 0; j < 4; j++)
                    acc[i][j] += ar[i] * wr[j];
        }
    }

    const float c0 = 0.7978845608028654f, c1 = 0.044715f;
#pragma unroll
    for (int i = 0; i < 4; i++) {
        int row = row0 + ty * 4 + i;
        int rrow = resIdx ? resIdx[row] : row;
#pragma unroll
        for (int j = 0; j < 4; j++) {
            int col = col0 + tx * 4 + j;
            float v = acc[i][j];
            if (bias) v += bias[col];
            if (res)  v += res[(size_t)rrow * N + col];
            if (act == 1) v = fmaxf(v, 0.0f);
            else if (act == 2) { float t = v; v = 0.5f * t * (1.0f + tanhf(c0 * (t + c1 * t * t * t))); }
            if (dstIdx) atomicAdd(&out[(size_t)dstIdx[row] * N + col], v);
            else out[(size_t)row * N + col] = v;
        }
    }
}

// ---------------- 128x128 tile, 8x8 micro-tile fp32 GEMM (for big GEMMs) ----------------
// out[M,N] = act(A[M,K] @ W[K,N] + bias[N] + res[M,N]); M%128==0, N%128==0, K%16==0
__global__ __launch_bounds__(256, 3) void gemm128(
    const float* __restrict__ A, const float* __restrict__ W,
    const float* __restrict__ bias, const float* __restrict__ res,
    float* __restrict__ out, int M, int N, int K, int act)
{
    __shared__ float As[16][132];   // [k][row]
    __shared__ float Ws[16][132];   // [k][col]
    int tid = threadIdx.x;
    int row0 = blockIdx.x * 128, col0 = blockIdx.y * 128;
    int ty = tid >> 4, tx = tid & 15;       // 16x16 threads
    float acc[8][8] = {};

    for (int kc = 0; kc < K; kc += 16) {
        float4 av[2], wv[2];
#pragma unroll
        for (int q = 0; q < 2; q++) {
            int fidx = q * 256 + tid;           // 0..511
            int arow = fidx >> 2;               // 0..127
            int ak4  = (fidx & 3) * 4;          // 0,4,8,12
            av[q] = *(const float4*)&A[(size_t)(row0 + arow) * K + kc + ak4];
            int wrow = fidx >> 5;               // 0..15
            int wc4  = (fidx & 31) * 4;         // 0..124
            wv[q] = *(const float4*)&W[(size_t)(kc + wrow) * N + col0 + wc4];
        }
        __syncthreads();
#pragma unroll
        for (int q = 0; q < 2; q++) {
            int fidx = q * 256 + tid;
            int arow = fidx >> 2;
            int ak4  = (fidx & 3) * 4;
            As[ak4 + 0][arow] = av[q].x;
            As[ak4 + 1][arow] = av[q].y;
            As[ak4 + 2][arow] = av[q].z;
            As[ak4 + 3][arow] = av[q].w;
            int wrow = fidx >> 5;
            int wc4  = (fidx & 31) * 4;
            *(float4*)&Ws[wrow][wc4] = wv[q];
        }
        __syncthreads();
#pragma unroll
        for (int kk = 0; kk < 16; kk++) {
            float4 aA = *(const float4*)&As[kk][ty * 4];
            float4 aB = *(const float4*)&As[kk][64 + ty * 4];
            float4 wA = *(const float4*)&Ws[kk][tx * 4];
            float4 wB = *(const float4*)&Ws[kk][64 + tx * 4];
            float ar[8] = {aA.x, aA.y, aA.z, aA.w, aB.x, aB.y, aB.z, aB.w};
            float wr[8] = {wA.x, wA.y, wA.z, wA.w, wB.x, wB.y, wB.z, wB.w};
#pragma unroll
            for (int i = 0; i < 8; i++)
#pragma unroll
                for (int j = 0; j < 8; j++)
                    acc[i][j] += ar[i] * wr[j];
        }
    }

    const float c0 = 0.7978845608028654f, c1 = 0.044715f;
#pragma unroll
    for (int i = 0; i < 8; i++) {
        int row = row0 + (i < 4 ? ty * 4 + i : 64 + ty * 4 + (i - 4));
#pragma unroll
        for (int j = 0; j < 8; j++) {
            int col = col0 + (j < 4 ? tx * 4 + j : 64 + tx * 4 + (j - 4));
            float v = acc[i][j];
            if (bias) v += bias[col];
            if (res)  v += res[(size_t)row * N + col];
            if (act == 1) v = fmaxf(v, 0.0f);
            else if (act == 2) { float t = v; v = 0.5f * t * (1.0f + tanhf(c0 * (t + c1 * t * t * t))); }
            out[(size_t)row * N + col] = v;
        }
    }
}

// ---------------- per-edge attention (S=8, NH=4, hd=64) ----------------
__global__ __launch_bounds__(256) void k_attn(const float* __restrict__ q,
                                              const float* __restrict__ k,
                                              const float* __restrict__ v,
                                              float* __restrict__ o) {
    __shared__ float qs[8 * 256], ks[8 * 256], vs[8 * 256];
    __shared__ float sc[4 * 8 * 8];
    int b = blockIdx.x, t = threadIdx.x;
    const size_t base = (size_t)b * (8 * 256);
    for (int i = t; i < 2048; i += 256) { qs[i] = q[base + i]; ks[i] = k[base + i]; vs[i] = v[base + i]; }
    __syncthreads();
    {
        int h = t >> 6, sq = (t >> 3) & 7, sk = t & 7;
        float acc = 0.0f;
#pragma unroll
        for (int d = 0; d < 64; d++) acc += qs[sq * 256 + h * 64 + d] * ks[sk * 256 + h * 64 + d];
        sc[t] = acc * 0.125f;     // 1/sqrt(64)
    }
    __syncthreads();
    if (t < 32) {
        int h = t >> 3, sq = t & 7;
        float* r = &sc[h * 64 + sq * 8];
        float M = r[0];
        for (int i = 1; i < 8; i++) M = fmaxf(M, r[i]);
        float S = 0.0f, ex[8];
        for (int i = 0; i < 8; i++) { ex[i] = __expf(r[i] - M); S += ex[i]; }
        float inv = 1.0f / S;
        for (int i = 0; i < 8; i++) r[i] = ex[i] * inv;
    }
    __syncthreads();
    {
        int col = t; int h = col >> 6;
#pragma unroll
        for (int sq = 0; sq < 8; sq++) {
            float a = 0.0f;
#pragma unroll
            for (int sk = 0; sk < 8; sk++) a += sc[h * 64 + sq * 8 + sk] * vs[sk * 256 + col];
            o[base + sq * 256 + col] = a;
        }
    }
}

// ---------------- logits = y @ emb^T into probs: K=64 single-stage tiled GEMM ----------------
// 128x128 tile, 8x8 micro. Both operands staged once in LDS ([k][row/col] transposed),
// one barrier, 64 fully-in-LDS k-steps: 4 conflict-free ds_read_b128 + 64 FMA per step.
// grid = (NROWS/128, ceil(VOCAB/128)) = (128, 79).
__global__ __launch_bounds__(256, 2) void k_logits(const float* __restrict__ Y,
                                                   const float* __restrict__ emb,
                                                   float* __restrict__ probs) {
    __shared__ float As[64][132];   // [k][row]  33 KB
    __shared__ float Ws[64][132];   // [k][col]  33 KB
    int t = threadIdx.x;
    int ty = t >> 4, tx = t & 15;
    int r0 = blockIdx.x * 128;
    int c0 = blockIdx.y * 128;

    // stage Y[r0..+127][0..63] -> As[k][row]   (coalesced global, once)
#pragma unroll
    for (int q = 0; q < 8; q++) {
        int fidx = q * 256 + t;            // 0..2047
        int row = fidx >> 4;               // 0..127
        int k4  = (fidx & 15) * 4;         // 0..60
        float4 a4 = *(const float4*)&Y[(size_t)(r0 + row) * DIM + k4];
        As[k4 + 0][row] = a4.x;
        As[k4 + 1][row] = a4.y;
        As[k4 + 2][row] = a4.z;
        As[k4 + 3][row] = a4.w;
    }
    // stage emb[c0..+127][0..63] -> Ws[k][col] (clamped at vocab tail)
#pragma unroll
    for (int q = 0; q < 8; q++) {
        int fidx = q * 256 + t;
        int col = fidx >> 4;               // 0..127
        int k4  = (fidx & 15) * 4;
        int v = c0 + col; if (v >= VOCAB) v = VOCAB - 1;
        float4 e4 = *(const float4*)&emb[(size_t)v * DIM + k4];
        Ws[k4 + 0][col] = e4.x;
        Ws[k4 + 1][col] = e4.y;
        Ws[k4 + 2][col] = e4.z;
        Ws[k4 + 3][col] = e4.w;
    }
    __syncthreads();

    float acc[8][8] = {};
#pragma unroll 16
    for (int kk = 0; kk < 64; kk++) {
        float4 aA = *(const float4*)&As[kk][ty * 4];
        float4 aB = *(const float4*)&As[kk][64 + ty * 4];
        float4 wA = *(const float4*)&Ws[kk][tx * 4];
        float4 wB = *(const float4*)&Ws[kk][64 + tx * 4];
        float ar[8] = {aA.x, aA.y, aA.z, aA.w, aB.x, aB.y, aB.z, aB.w};
        float wr[8] = {wA.x, wA.y, wA.z, wA.w, wB.x, wB.y, wB.z, wB.w};
#pragma unroll
        for (int i = 0; i < 8; i++)
#pragma unroll
            for (int j = 0; j < 8; j++)
                acc[i][j] += ar[i] * wr[j];
    }

    // epilogue: float4 stores, masked at vocab tail (VOCAB%4==0 -> group all-or-nothing)
    int colA = c0 + tx * 4;
    int colB = colA + 64;
    bool okA = colA < VOCAB, okB = colB < VOCAB;
#pragma unroll
    for (int i = 0; i < 8; i++) {
        int row = r0 + (i < 4 ? ty * 4 + i : 64 + ty * 4 + (i - 4));
        float* pr = &probs[(size_t)row * VOCAB];
        if (okA) { float4 o4 = {acc[i][0], acc[i][1], acc[i][2], acc[i][3]}; *(float4*)&pr[colA] = o4; }
        if (okB) { float4 o4 = {acc[i][4], acc[i][5], acc[i][6], acc[i][7]}; *(float4*)&pr[colB] = o4; }
    }
}

// ---------------- in-place row softmax over VOCAB (row cached in LDS) ----------------
__global__ __launch_bounds__(256) void k_softmax(float* __restrict__ probs) {
    __shared__ float4 sdata[VOCAB / 4];   // 2500 float4 = 40000 B
    __shared__ float wred[8];
    int t = threadIdx.x;
    float4* prow = (float4*)&probs[(size_t)blockIdx.x * VOCAB];

    // pass 1: load + local max
    float m = -1e30f;
#pragma unroll
    for (int i = 0; i < 10; i++) {
        int j = t + 256 * i;
        if (j < VOCAB / 4) {
            float4 v4 = prow[j];
            sdata[j] = v4;
            m = fmaxf(fmaxf(fmaxf(m, v4.x), v4.y), fmaxf(v4.z, v4.w));
        }
    }
#pragma unroll
    for (int off = 32; off; off >>= 1) m = fmaxf(m, __shfl_xor(m, off, 64));
    if ((t & 63) == 0) wred[t >> 6] = m;
    __syncthreads();
    float M = fmaxf(fmaxf(wred[0], wred[1]), fmaxf(wred[2], wred[3]));

    // pass 2: exp + local sum (store exp back to LDS)
    float s = 0.0f;
#pragma unroll
    for (int i = 0; i < 10; i++) {
        int j = t + 256 * i;
        if (j < VOCAB / 4) {
            float4 v4 = sdata[j];
            v4.x = __expf(v4.x - M); v4.y = __expf(v4.y - M);
            v4.z = __expf(v4.z - M); v4.w = __expf(v4.w - M);
            sdata[j] = v4;
            s += v4.x + v4.y + v4.z + v4.w;
        }
    }
#pragma unroll
    for (int off = 32; off; off >>= 1) s += __shfl_xor(s, off, 64);
    if ((t & 63) == 0) wred[4 + (t >> 6)] = s;
    __syncthreads();
    float Sinv = 1.0f / (wred[4] + wred[5] + wred[6] + wred[7]);

    // pass 3: scale + store
#pragma unroll
    for (int i = 0; i < 10; i++) {
        int j = t + 256 * i;
        if (j < VOCAB / 4) {
            float4 v4 = sdata[j];
            v4.x *= Sinv; v4.y *= Sinv; v4.z *= Sinv; v4.w *= Sinv;
            prow[j] = v4;
        }
    }
}

extern "C" void kernel_launch(void* const* d_in, const int* in_sizes, int n_in,
                              void* d_out, int out_size, void* d_ws, size_t ws_size,
                              hipStream_t stream) {
    const int* node_tokens = (const int*)d_in[0];
    const int* edge_tokens = (const int*)d_in[1];
    const int* edge_index  = (const int*)d_in[2];
    const int* mask_rows   = (const int*)d_in[3];   // bool passed as int32
    const float* emb    = (const float*)d_in[4];
    const float* W_msg  = (const float*)d_in[5];
    const float* W_node = (const float*)d_in[6];
    const float* lc1_w  = (const float*)d_in[7];
    const float* lc1_b  = (const float*)d_in[8];
    const float* lc2_w  = (const float*)d_in[9];
    const float* lc2_b  = (const float*)d_in[10];
    const float* Wq     = (const float*)d_in[11];
    const float* Wk     = (const float*)d_in[12];
    const float* Wv     = (const float*)d_in[13];
    const float* Wo     = (const float*)d_in[14];
    const float* Wf1    = (const float*)d_in[15];
    const float* Wf2    = (const float*)d_in[16];

    const int* src = edge_index;
    const int* dst = edge_index + NEDGES;

    float* labels = (float*)d_out;
    float* probs  = labels + NROWS;

    float* ws = (float*)d_ws;
    float* X   = ws;                  // [8192,512]
    float* E_  = X   + 4194304;       // [2048,512]
    float* AGG = E_  + 1048576;       // [8192,512], becomes H in-place
    float* EH  = AGG + 4194304;       // [2048,512] == z rows [16384,64]
    float* Z1  = EH  + 1048576;       // [16384,256]
    float* Q_  = Z1  + 4194304;
    float* K_  = Q_  + 4194304;
    float* Vv  = K_  + 4194304;
    float* O_  = Vv  + 4194304;
    float* X2  = O_  + 4194304;
    float* U_  = X2  + 4194304;       // [16384,1024]
    float* Y2  = U_  + 16777216;      // [16384,256]
    float* Y_  = Y2  + 4194304;       // [16384,64]
    int*  MTOK = (int*)(Y_ + 1048576);

    // zero agg for scatter-add
    hipMemsetAsync(AGG, 0, (size_t)NNODES * FDIM * sizeof(float), stream);

    // masking + labels
    k_mask<<<NROWS / 256, 256, 0, stream>>>(edge_tokens, mask_rows, labels, MTOK);

    // embeddings
    k_embed<<<(NNODES * FDIM) / 256, 256, 0, stream>>>(node_tokens, emb, X, NNODES * FDIM);
    k_embed<<<(NEDGES * FDIM) / 256, 256, 0, stream>>>(MTOK, emb, E_, NEDGES * FDIM);

    // msg = relu(e @ W_msg + x[src]); scatter-add to agg[dst]
    gemm_kernel<<<dim3(NEDGES / 64, FDIM / 64), 256, 0, stream>>>(
        E_, W_msg, nullptr, X, src, dst, AGG, NEDGES, FDIM, FDIM, 1);

    // h = relu(x @ W_node + agg)   (in-place into AGG) — big GEMM, 128-tile
    gemm128<<<dim3(NNODES / 128, FDIM / 128), 256, 0, stream>>>(
        X, W_node, nullptr, AGG, AGG, NNODES, FDIM, FDIM, 1);

    // eh = h[src] + h[dst]
    k_eh<<<(NEDGES * FDIM) / 256, 256, 0, stream>>>(AGG, src, dst, EH);

    // z1 = eh @ lc1_w + lc1_b    ([16384,64] @ [64,256])
    gemm_kernel<<<dim3(NROWS / 64, DGPT / 64), 256, 0, stream>>>(
        EH, lc1_w, lc1_b, nullptr, nullptr, nullptr, Z1, NROWS, DGPT, DIM, 0);

    // q,k,v projections
    gemm_kernel<<<dim3(NROWS / 64, DGPT / 64), 256, 0, stream>>>(
        Z1, Wq, nullptr, nullptr, nullptr, nullptr, Q_, NROWS, DGPT, DGPT, 0);
    gemm_kernel<<<dim3(NROWS / 64, DGPT / 64), 256, 0, stream>>>(
        Z1, Wk, nullptr, nullptr, nullptr, nullptr, K_, NROWS, DGPT, DGPT, 0);
    gemm_kernel<<<dim3(NROWS / 64, DGPT / 64), 256, 0, stream>>>(
        Z1, Wv, nullptr, nullptr, nullptr, nullptr, Vv, NROWS, DGPT, DGPT, 0);

    // attention
    k_attn<<<NEDGES, 256, 0, stream>>>(Q_, K_, Vv, O_);

    // x2 = z1 + o @ Wo
    gemm_kernel<<<dim3(NROWS / 64, DGPT / 64), 256, 0, stream>>>(
        O_, Wo, nullptr, Z1, nullptr, nullptr, X2, NROWS, DGPT, DGPT, 0);

    // u = gelu(x2 @ Wf1) — big GEMM, 128-tile
    gemm128<<<dim3(NROWS / 128, (4 * DGPT) / 128), 256, 0, stream>>>(
        X2, Wf1, nullptr, nullptr, U_, NROWS, 4 * DGPT, DGPT, 2);

    // y2 = x2 + u @ Wf2 — big GEMM, 128-tile
    gemm128<<<dim3(NROWS / 128, DGPT / 128), 256, 0, stream>>>(
        U_, Wf2, nullptr, X2, Y2, NROWS, DGPT, 4 * DGPT, 0);

    // y = y2 @ lc2_w + lc2_b
    gemm_kernel<<<dim3(NROWS / 64, DIM / 64), 256, 0, stream>>>(
        Y2, lc2_w, lc2_b, nullptr, nullptr, nullptr, Y_, NROWS, DIM, DGPT, 0);

    // logits into probs buffer (single-stage K=64 GEMM), then in-place row softmax
    k_logits<<<dim3(NROWS / 128, (VOCAB + 127) / 128), 256, 0, stream>>>(Y_, emb, probs);
    k_softmax<<<NROWS, 256, 0, stream>>>(probs);
}